// Round 22
// baseline (7736.469 us; speedup 1.0000x reference)
//
#include <hip/hip_runtime.h>
#include <math.h>
#include <float.h>

#define KE 8192        // number of edges
#define NPF 3072       // floats per edge (1024 * 3)
#define NT 512         // threads (8 waves, all run the chain redundantly)
#define EPT 16         // edges per thread
#define NW  8          // waves
#define TOPK_N 10
#define KNN 64         // candidates per list (2 windows x 2 x 32 lanes)
#define TAIL_T 7167    // main loop steps; live at tail start = 1024

typedef unsigned long long u64;
typedef unsigned short u16;
typedef float v2f __attribute__((ext_vector_type(2)));

#define GETP(arr, k) (((k) & 1) ? arr[(k) >> 1].y : arr[(k) >> 1].x)

#define DPPMIN(x, ctrl, rmask)                                              \
  do {                                                                      \
    unsigned _t = (unsigned)__builtin_amdgcn_update_dpp(                    \
        (int)0xFFFFFFFF, (int)(x), (ctrl), (rmask), 0xf, false);            \
    (x) = ((x) < _t) ? (x) : _t;                                            \
  } while (0)

#define RDL(v, l) __uint_as_float((unsigned)__builtin_amdgcn_readlane(__float_as_int(v), (l)))

// numpy-exact squared distance (no contraction) for DISCRETE decisions
__device__ __forceinline__ float dist2(float ax, float ay, float az,
                                       float bx, float by, float bz) {
#pragma clang fp contract(off)
  float dx = ax - bx, dy = ay - by, dz = az - bz;
  float s = (dx * dx + dy * dy) + dz * dz;
  return s;
}

// packed 2-edge squared distance, FMA form (argmin-safe; certified by bench)
__device__ __forceinline__ v2f dist2p(v2f cx, v2f cy, v2f cz,
                                      v2f px, v2f py, v2f pz) {
  v2f dx = px - cx, dy = py - cy, dz = pz - cz;
  return __builtin_elementwise_fma(dx, dx,
           __builtin_elementwise_fma(dy, dy, dz * dz));
}

// scalar twin of dist2p: IDENTICAL dataflow -> bitwise-identical values
__device__ __forceinline__ float dist2f(float cx, float cy, float cz,
                                        float px, float py, float pz) {
  float dx = px - cx, dy = py - cy, dz = pz - cz;
  return fmaf(dx, dx, fmaf(dy, dy, dz * dz));
}

__device__ __forceinline__ float dist3(float ax, float ay, float az,
                                       float bx, float by, float bz) {
  return sqrtf(dist2(ax, ay, az, bx, by, bz));
}

__device__ __forceinline__ u64 umin64(u64 a, u64 b) { return a < b ? a : b; }

// ---- build the compact 32B/edge endpoint table ----
extern "C" __global__ void __launch_bounds__(256)
tbl_build_kernel(const float* __restrict__ edges, float4* __restrict__ tbl4)
{
  int e = blockIdx.x * 256 + threadIdx.x;    // 8192 threads
  const float* p = edges + (size_t)e * NPF;
  float4 a, b;
  a.x = p[0]; a.y = p[1]; a.z = p[2]; a.w = p[NPF - 3];
  b.x = p[NPF - 2]; b.y = p[NPF - 1]; b.z = 0.f; b.w = 0.f;
  tbl4[(size_t)e * 2]     = a;
  tbl4[(size_t)e * 2 + 1] = b;
}

// ---- per-endpoint 64-NN edge lists (u16 indices, order = key order) ----
// f64-bitcast insertion: keys positive normals -> fmin/fmax == u64 order.
// 256-thread blocks (4 waves/CU) give the TLP to hide L2 load latency.
extern "C" __global__ void __launch_bounds__(256)
knn_kernel(const float4* __restrict__ tbl4, u16* __restrict__ lists)
{
  const int q = blockIdx.x * 256 + threadIdx.x;   // 16384 points
  float px, py, pz;
  {
    const float4* tp = tbl4 + (size_t)(q & (KE - 1)) * 2;
    float4 a = tp[0], b = tp[1];
    if (q < KE) { px = a.x; py = a.y; pz = a.z; }
    else        { px = a.w; py = b.x; pz = b.y; }
  }
  const double SENT = __longlong_as_double(0x7FE0000000000000LL); // max finite
  double kk[KNN];
#pragma unroll
  for (int i = 0; i < KNN; ++i) kk[i] = SENT;

#pragma unroll 4
  for (int e = 0; e < KE; ++e) {
    float4 a = tbl4[(size_t)e * 2];
    float4 b = tbl4[(size_t)e * 2 + 1];
    float d2s = dist2f(px, py, pz, a.x, a.y, a.z);
    float d2e = dist2f(px, py, pz, a.w, b.x, b.y);
    float v = fminf(d2s, d2e);
    double key = __longlong_as_double(
        (long long)(((u64)__float_as_uint(v) << 32) | (unsigned)e));
    if (key < kk[KNN - 1]) {
      double c = key;
#pragma unroll
      for (int j = 0; j < KNN; ++j) {
        double lo = fmin(kk[j], c);
        c         = fmax(kk[j], c);
        kk[j] = lo;
      }
    }
  }
  u16* lp = lists + (size_t)q * KNN;
#pragma unroll
  for (int i = 0; i < KNN; ++i)
    lp[i] = (u16)((u64)__double_as_longlong(kk[i]) & 0xFFFFu);
}

// R15-proven single-wave tail over the compacted 1024-entry LDS table.
__device__ void chain_tail(float& cxr, float& cyr, float& czr,
    unsigned* pk_lds, unsigned* d2_lds,
    const float4* s_ta, const float4* s_tb, int lane)
{
  constexpr int E = 16, NPT = 8;
  const int base = lane * E;
  v2f sxp[NPT], syp[NPT], szp[NPT], exp_[NPT], eyp[NPT], ezp[NPT];

#pragma unroll
  for (int e = 0; e < E; ++e) {
    float4 a = s_ta[base + e];
    float4 b = s_tb[base + e];
    if (e & 1) {
      sxp[e >> 1].y = a.x; syp[e >> 1].y = a.y; szp[e >> 1].y = a.z;
      exp_[e >> 1].y = a.w; eyp[e >> 1].y = b.x; ezp[e >> 1].y = b.y;
    } else {
      sxp[e >> 1].x = a.x; syp[e >> 1].x = a.y; szp[e >> 1].x = a.z;
      exp_[e >> 1].x = a.w; eyp[e >> 1].x = b.x; ezp[e >> 1].x = b.y;
    }
  }

  float cx = cxr, cy = cyr, cz = czr;

  for (int t = TAIL_T; t < KE - 1; ++t) {
    v2f cx2 = {cx, cx}, cy2 = {cy, cy}, cz2 = {cz, cz};
    float av0 = INFINITY, av1 = INFINITY, av2 = INFINITY, av3 = INFINITY;
    int   ai0 = 0, ai1 = 0, ai2 = 0, ai3 = 0;
#pragma unroll
    for (int p = 0; p < NPT; ++p) {
      v2f d2s = dist2p(cx2, cy2, cz2, sxp[p], syp[p], szp[p]);
      v2f d2e = dist2p(cx2, cy2, cz2, exp_[p], eyp[p], ezp[p]);
      v2f dm = __builtin_elementwise_min(d2s, d2e);
      int ix = base + 2 * p;
      int iy = base + 2 * p + 1;
      if ((p & 1) == 0) {
        if (dm.x < av0) { av0 = dm.x; ai0 = ix; }
        if (dm.y < av2) { av2 = dm.y; ai2 = iy; }
      } else {
        if (dm.x < av1) { av1 = dm.x; ai1 = ix; }
        if (dm.y < av3) { av3 = dm.y; ai3 = iy; }
      }
    }
    float mv = av0; int mi = ai0;
    if (av1 < mv || (av1 == mv && ai1 < mi)) { mv = av1; mi = ai1; }
    if (av2 < mv || (av2 == mv && ai2 < mi)) { mv = av2; mi = ai2; }
    if (av3 < mv || (av3 == mv && ai3 < mi)) { mv = av3; mi = ai3; }

    unsigned mvb = __float_as_uint(mv);
    unsigned x = mvb;
    DPPMIN(x, 0x111, 0xf);
    DPPMIN(x, 0x112, 0xf);
    DPPMIN(x, 0x114, 0xf);
    DPPMIN(x, 0x118, 0xf);
    DPPMIN(x, 0x142, 0xa);
    DPPMIN(x, 0x143, 0xc);
    unsigned wmin = (unsigned)__builtin_amdgcn_readlane((int)x, 63);

    u64 ball = __ballot(mvb == wmin);
    int win_lane = __ffsll(ball) - 1;
    int wpos = __builtin_amdgcn_readlane(mi, win_lane);

    float4 a = s_ta[wpos];
    float4 b = s_tb[wpos];
    int orig = __float_as_int(b.z);

    float da2 = dist2(cx, cy, cz, a.x, a.y, a.z);
    float db2 = dist2(cx, cy, cz, a.w, b.x, b.y);
    int fl = (sqrtf(da2) > sqrtf(db2)) ? 1 : 0;
    cx = fl ? a.x : a.w;
    cy = fl ? a.y : b.x;
    cz = fl ? a.z : b.y;

    if (lane == win_lane) {
      int e = wpos & (E - 1);
#pragma unroll
      for (int k = 0; k < NPT; ++k) {
        if ((e >> 1) == k) {
          if (e & 1) { sxp[k].y = INFINITY; exp_[k].y = INFINITY; }
          else       { sxp[k].x = INFINITY; exp_[k].x = INFINITY; }
        }
      }
      pk_lds[t + 1] = ((unsigned)orig << 1) | (unsigned)fl;
      d2_lds[t]     = wmin;
    }
  }

  cxr = cx; cyr = cy; czr = cz;
}

extern "C" __global__ void __launch_bounds__(NT, 1)
chain_kernel(const float* __restrict__ edges, float* __restrict__ tail,
             int* __restrict__ ws_order, int* __restrict__ ws_flip,
             float* __restrict__ tbl, const u16* __restrict__ lists)
{
  const int tid = threadIdx.x;
  const int lane = tid & 63;
  const int wid = tid >> 6;          // 0..7
  const int base = tid * EPT;
  const float4* tbl4 = (const float4*)tbl;

  __shared__ __align__(16) u64 kbuf[NW];
  __shared__ float  s_v[NW];
  __shared__ int    s_i[NW];
  __shared__ float  s_m1[NW], s_m2[NW];
  __shared__ unsigned pk_lds[KE];
  __shared__ unsigned d2_lds[KE];
  __shared__ unsigned bm[NW][KE / 32];          // per-WAVE private bitmaps
  __shared__ __align__(16) float4 s_ta[1024];   // tail coord table
  __shared__ __align__(16) float4 s_tb[1024];

  // zero this wave's private bitmap
  for (int i = lane; i < KE / 32; i += 64) bm[wid][i] = 0u;

  // ---- init: load endpoints into registers (512 threads x 16 edges) ----
  v2f sxp[EPT / 2], syp[EPT / 2], szp[EPT / 2];
  v2f exp_[EPT / 2], eyp[EPT / 2], ezp[EPT / 2];
#pragma unroll
  for (int e = 0; e < EPT; ++e) {
    const float* p = edges + (size_t)(base + e) * NPF;
    float a0 = p[0], a1 = p[1], a2 = p[2];
    float b0 = p[NPF - 3], b1 = p[NPF - 2], b2 = p[NPF - 1];
    if (e & 1) {
      sxp[e >> 1].y = a0; syp[e >> 1].y = a1; szp[e >> 1].y = a2;
      exp_[e >> 1].y = b0; eyp[e >> 1].y = b1; ezp[e >> 1].y = b2;
    } else {
      sxp[e >> 1].x = a0; syp[e >> 1].x = a1; szp[e >> 1].x = a2;
      exp_[e >> 1].x = b0; eyp[e >> 1].x = b1; ezp[e >> 1].x = b2;
    }
  }

  // ---- lengths; top-10; start_index = max index among them ----
  float len[EPT];
#pragma unroll
  for (int e = 0; e < EPT; ++e)
    len[e] = dist3(GETP(exp_, e), GETP(eyp, e), GETP(ezp, e),
                   GETP(sxp, e), GETP(syp, e), GETP(szp, e));

  unsigned tk = 0;
  int start_index = -1;
  for (int r = 0; r < TOPK_N; ++r) {
    float bv = -INFINITY; int bi = 0x7fffffff;
#pragma unroll
    for (int e = 0; e < EPT; ++e) {
      if ((tk >> e) & 1) continue;
      if (len[e] > bv) { bv = len[e]; bi = base + e; }
    }
    for (int m = 1; m < 64; m <<= 1) {
      float v2 = __shfl_xor(bv, m); int i2 = __shfl_xor(bi, m);
      if (v2 > bv || (v2 == bv && i2 < bi)) { bv = v2; bi = i2; }
    }
    if (lane == 0) { s_v[wid] = bv; s_i[wid] = bi; }
    __syncthreads();
    {
      float cv = s_v[lane & (NW - 1)]; int ci = s_i[lane & (NW - 1)];
      for (int m = 1; m < NW; m <<= 1) {
        float v2 = __shfl_xor(cv, m); int i2 = __shfl_xor(ci, m);
        if (v2 > cv || (v2 == cv && i2 < ci)) { cv = v2; ci = i2; }
      }
      int sel = ci;
      if ((sel / EPT) == tid) tk |= 1u << (sel & (EPT - 1));
      if (sel > start_index) start_index = sel;
    }
    __syncthreads();
  }

  // ---- s0 / e0: uniform global load ----
  float s0x, s0y, s0z, e0x, e0y, e0z;
  {
    const float* p = edges + (size_t)start_index * NPF;
    s0x = p[0];       s0y = p[1];       s0z = p[2];
    e0x = p[NPF - 3]; e0y = p[NPF - 2]; e0z = p[NPF - 1];
  }

  // ---- use_flip0 (numpy-exact; sqrt(min)==min(sqrt)) ----
  {
    float m1 = INFINITY, m2 = INFINITY;
#pragma unroll
    for (int e = 0; e < EPT; ++e) {
      int k = base + e;
      float a = dist2(s0x, s0y, s0z, GETP(sxp, e), GETP(syp, e), GETP(szp, e));
      float b = dist2(s0x, s0y, s0z, GETP(exp_, e), GETP(eyp, e), GETP(ezp, e));
      float c = dist2(e0x, e0y, e0z, GETP(sxp, e), GETP(syp, e), GETP(szp, e));
      float d = dist2(e0x, e0y, e0z, GETP(exp_, e), GETP(eyp, e), GETP(ezp, e));
      float v1 = fminf(a, b), v2 = fminf(c, d);
      if (k == start_index) { v1 = INFINITY; v2 = INFINITY; }
      m1 = fminf(m1, v1);
      m2 = fminf(m2, v2);
    }
    for (int m = 1; m < 64; m <<= 1) {
      m1 = fminf(m1, __shfl_xor(m1, m));
      m2 = fminf(m2, __shfl_xor(m2, m));
    }
    if (lane == 0) { s_m1[wid] = m1; s_m2[wid] = m2; }
  }
  __syncthreads();

  float cx, cy, cz, fx, fy, fz;
  int flip0;
  {
    float m1 = s_m1[lane & (NW - 1)], m2 = s_m2[lane & (NW - 1)];
    for (int m = 1; m < NW; m <<= 1) {
      m1 = fminf(m1, __shfl_xor(m1, m));
      m2 = fminf(m2, __shfl_xor(m2, m));
    }
    flip0 = (sqrtf(m1) < sqrtf(m2)) ? 1 : 0;
    cx = flip0 ? s0x : e0x;  cy = flip0 ? s0y : e0y;  cz = flip0 ? s0z : e0z;
    fx = flip0 ? e0x : s0x;  fy = flip0 ? e0y : s0y;  fz = flip0 ? e0z : s0z;
    if (tid == 0)
      pk_lds[0] = ((unsigned)start_index << 1) | (unsigned)flip0;
  }
  // each wave marks start edge in ITS bitmap
  if (lane == 0)
    bm[wid][start_index >> 5] |= 1u << (start_index & 31);

  // ---- warm lists (2MB) + tbl (256KB) into this XCD's L2 ----
  if (lists) {
    const float4* lp = (const float4*)lists;
    float acc = 0.f;
    for (int i = tid; i < 131072 + 16384; i += NT) {
      float4 v = (i < 131072) ? lp[i] : tbl4[i - 131072];
      acc += v.x + v.y + v.z + v.w;
    }
    asm volatile("" :: "v"(acc));
  }

  // owner of start edge: poison + clear alive
  unsigned alive = 0xFFFFu;
  if (tid == (start_index >> 4)) {
    int e = start_index & (EPT - 1);
#pragma unroll
    for (int k = 0; k < EPT / 2; ++k) {
      if ((e >> 1) == k) {
        if (e & 1) { sxp[k].y = INFINITY; exp_[k].y = INFINITY; }
        else       { sxp[k].x = INFINITY; exp_[k].x = INFINITY; }
      }
    }
    alive &= ~(1u << e);
  }
  __syncthreads();

  // bootstrap prefetch: lanes 0-31 window A (point widx), 32-63 window B;
  // each lane holds list positions (lane&31) and (lane&31)+32.
  int pf0 = 0, pf1 = 0;
  if (lists) {
    int pid = (lane < 32) ? start_index : start_index + KE;
    pf0 = (int)lists[(size_t)pid * KNN + (lane & 31)];
    pf1 = (int)lists[(size_t)pid * KNN + 32 + (lane & 31)];
  }
  int fl_prev = flip0;

  // ========== main chain: hit path barrier-free, miss path R14 ==========
  for (int t = 0; t < TAIL_T; ++t) {
    int widx; unsigned wd2;
    bool hit = false;

    if (lists) {
      int klo0 = pf0, klo1 = pf1;
      // speculative coord load for first-half candidates only
      float4 ta = tbl4[(size_t)klo0 * 2];
      float4 tb = tbl4[(size_t)klo0 * 2 + 1];
      unsigned w0 = bm[wid][klo0 >> 5];
      unsigned w1 = bm[wid][klo1 >> 5];
      int actwin = fl_prev ? 0 : 1;        // fl=1 -> new endpoint = widx
      bool act = ((lane >> 5) == actwin);
      bool un0 = act && !((w0 >> (klo0 & 31)) & 1);
      bool un1 = act && !((w1 >> (klo1 & 31)) & 1);
      u64 b0 = __ballot(un0);
      u64 b1 = __ballot(un1);
      if (b0 | b1) {
        hit = true;                        // identical across waves
        float osx, osy, osz, oex, oey, oez;
        if (b0) {                          // positions 0-31 take priority
          int first = __ffsll(b0) - 1;
          widx = __builtin_amdgcn_readlane(klo0, first);
          osx = RDL(ta.x, first); osy = RDL(ta.y, first); osz = RDL(ta.z, first);
          oex = RDL(ta.w, first); oey = RDL(tb.x, first); oez = RDL(tb.y, first);
        } else {                           // positions 32-63 (rare)
          int first = __ffsll(b1) - 1;
          widx = __builtin_amdgcn_readlane(klo1, first);
          float4 a = tbl4[(size_t)widx * 2], b_ = tbl4[(size_t)widx * 2 + 1];
          osx = a.x; osy = a.y; osz = a.z; oex = a.w; oey = b_.x; oez = b_.y;
        }
        // early bitmap publish (settles next step's read dependency)
        if (lane == 0)
          bm[wid][widx >> 5] |= 1u << (widx & 31);
        // wd2: recompute with the key's exact dataflow (fmaf scalar twin)
        float d2s = dist2f(cx, cy, cz, osx, osy, osz);
        float d2e = dist2f(cx, cy, cz, oex, oey, oez);
        wd2 = __float_as_uint(fminf(d2s, d2e));
        // flip: numpy-exact
        float da2 = dist2(cx, cy, cz, osx, osy, osz);
        float db2 = dist2(cx, cy, cz, oex, oey, oez);
        int fl = (sqrtf(da2) > sqrtf(db2)) ? 1 : 0;
        cx = fl ? osx : oex;
        cy = fl ? osy : oey;
        cz = fl ? osz : oez;
        // prefetch next lists (both windows of winner)
        int pid = (lane < 32) ? widx : widx + KE;
        pf0 = (int)lists[(size_t)pid * KNN + (lane & 31)];
        pf1 = (int)lists[(size_t)pid * KNN + 32 + (lane & 31)];
        // bookkeeping: outputs (wave0) + owner poison
        if (wid == 0 && lane == 0) {
          pk_lds[t + 1] = ((unsigned)widx << 1) | (unsigned)fl;
          d2_lds[t] = wd2;
        }
        if (tid == (widx >> 4)) {
          int e = widx & (EPT - 1);
#pragma unroll
          for (int k = 0; k < EPT / 2; ++k) {
            if ((e >> 1) == k) {
              if (e & 1) { sxp[k].y = INFINITY; exp_[k].y = INFINITY; }
              else       { sxp[k].x = INFINITY; exp_[k].x = INFINITY; }
            }
          }
          alive &= ~(1u << e);
        }
        fl_prev = fl;
      }
    }

    if (!hit) {
      // uniform across waves -> barriers are safe. R14 scan machinery.
      v2f cx2 = {cx, cx}, cy2 = {cy, cy}, cz2 = {cz, cz};
      float av0 = INFINITY, av1 = INFINITY, av2 = INFINITY, av3 = INFINITY;
      int   ai0 = 0, ai1 = 0, ai2 = 0, ai3 = 0;
#pragma unroll
      for (int p = 0; p < EPT / 2; ++p) {
        v2f d2s = dist2p(cx2, cy2, cz2, sxp[p], syp[p], szp[p]);
        v2f d2e = dist2p(cx2, cy2, cz2, exp_[p], eyp[p], ezp[p]);
        v2f dm = __builtin_elementwise_min(d2s, d2e);
        int ix = base + 2 * p;
        int iy = base + 2 * p + 1;
        if ((p & 1) == 0) {
          if (dm.x < av0) { av0 = dm.x; ai0 = ix; }
          if (dm.y < av2) { av2 = dm.y; ai2 = iy; }
        } else {
          if (dm.x < av1) { av1 = dm.x; ai1 = ix; }
          if (dm.y < av3) { av3 = dm.y; ai3 = iy; }
        }
      }
      float mv = av0; int mi = ai0;
      if (av1 < mv || (av1 == mv && ai1 < mi)) { mv = av1; mi = ai1; }
      if (av2 < mv || (av2 == mv && ai2 < mi)) { mv = av2; mi = ai2; }
      if (av3 < mv || (av3 == mv && ai3 < mi)) { mv = av3; mi = ai3; }

      unsigned mvb = __float_as_uint(mv);
      unsigned x = mvb;
      DPPMIN(x, 0x111, 0xf);
      DPPMIN(x, 0x112, 0xf);
      DPPMIN(x, 0x114, 0xf);
      DPPMIN(x, 0x118, 0xf);
      DPPMIN(x, 0x142, 0xa);
      DPPMIN(x, 0x143, 0xc);
      unsigned wmin = (unsigned)__builtin_amdgcn_readlane((int)x, 63);
      u64 ball2 = __ballot(mvb == wmin);
      int win_lane = __ffsll(ball2) - 1;
      if (lane == win_lane)
        kbuf[wid] = ((u64)wmin << 32) | (unsigned)mi;
      __syncthreads();
      const ulonglong2* kp = (const ulonglong2*)&kbuf[0];
      ulonglong2 q0 = kp[0], q1 = kp[1], q2 = kp[2], q3 = kp[3];
      u64 kb = umin64(umin64(umin64(q0.x, q0.y), umin64(q1.x, q1.y)),
                      umin64(umin64(q2.x, q2.y), umin64(q3.x, q3.y)));
      widx = __builtin_amdgcn_readfirstlane((int)(kb & 0xFFFFFFFFu));
      wd2 = (unsigned)(kb >> 32);
      __syncthreads();               // protect kbuf reuse across wave skew

      // winner coords: uniform tbl load (miss is rare)
      float osx, osy, osz, oex, oey, oez;
      if (tbl4) {
        float4 a = tbl4[(size_t)widx * 2], b = tbl4[(size_t)widx * 2 + 1];
        osx = a.x; osy = a.y; osz = a.z; oex = a.w; oey = b.x; oez = b.y;
      } else {
        const float* wp = edges + (size_t)widx * NPF;
        osx = wp[0]; osy = wp[1]; osz = wp[2];
        oex = wp[NPF - 3]; oey = wp[NPF - 2]; oez = wp[NPF - 1];
      }
      float da2 = dist2(cx, cy, cz, osx, osy, osz);
      float db2 = dist2(cx, cy, cz, oex, oey, oez);
      int fl = (sqrtf(da2) > sqrtf(db2)) ? 1 : 0;
      cx = fl ? osx : oex;
      cy = fl ? osy : oey;
      cz = fl ? osz : oez;

      if (lane == 0) {
        bm[wid][widx >> 5] |= 1u << (widx & 31);
        if (wid == 0) {
          pk_lds[t + 1] = ((unsigned)widx << 1) | (unsigned)fl;
          d2_lds[t] = wd2;
        }
      }
      if (tid == (widx >> 4)) {
        int e = widx & (EPT - 1);
#pragma unroll
        for (int k = 0; k < EPT / 2; ++k) {
          if ((e >> 1) == k) {
            if (e & 1) { sxp[k].y = INFINITY; exp_[k].y = INFINITY; }
            else       { sxp[k].x = INFINITY; exp_[k].x = INFINITY; }
          }
        }
        alive &= ~(1u << e);
      }
      if (lists) {
        int pid = (lane < 32) ? widx : widx + KE;
        pf0 = (int)lists[(size_t)pid * KNN + (lane & 31)];
        pf1 = (int)lists[(size_t)pid * KNN + 32 + (lane & 31)];
      }
      fl_prev = fl;
    }
  }

  // ---- compacted LDS table (1024 live, ascending original index) ----
  __syncthreads();
  {
    int cnt = __popc(alive);
    int sc = cnt;
#pragma unroll
    for (int m = 1; m < 64; m <<= 1) {
      int o = __shfl_up(sc, m);
      if (lane >= m) sc += o;
    }
    if (lane == 63) s_i[wid] = sc;
    __syncthreads();
    int wbase = 0;
#pragma unroll
    for (int w = 0; w < NW; ++w)
      if (w < wid) wbase += s_i[w];
    int pos = wbase + sc - cnt;
#pragma unroll
    for (int e = 0; e < EPT; ++e) {
      if ((alive >> e) & 1) {
        float4 a, b;
        a.x = GETP(sxp, e); a.y = GETP(syp, e); a.z = GETP(szp, e);
        a.w = GETP(exp_, e);
        b.x = GETP(eyp, e); b.y = GETP(ezp, e);
        b.z = __int_as_float(base + e); b.w = 0.f;
        s_ta[pos] = a; s_tb[pos] = b; ++pos;
      }
    }
  }
  __syncthreads();

  // ---- tail: compacted single-wave scan (proven R15 structure) ----
  if (wid == 0) {
    chain_tail(cx, cy, cz, pk_lds, d2_lds, s_ta, s_tb, lane);
    if (lane == 0)
      d2_lds[KE - 1] = __float_as_uint(dist2(cx, cy, cz, fx, fy, fz));
  }
  __syncthreads();

  // ---- final flush: LDS -> global (order | flips | distances | ws) ----
  float* ord_f = tail;
  float* flp_f = tail + KE;
  float* dst_f = tail + 2 * KE;
#pragma unroll
  for (int k = 0; k < EPT; ++k) {
    int i = tid + k * NT;
    unsigned p = pk_lds[i];
    int w = (int)(p >> 1);
    int f = (int)(p & 1u);
    ord_f[i] = (float)w;
    flp_f[i] = (float)f;
    dst_f[i] = sqrtf(__uint_as_float(d2_lds[i]));
    ws_order[i] = w;
    ws_flip[i]  = f;
  }
}

extern "C" __global__ void __launch_bounds__(256)
gather_kernel(const float* __restrict__ edges, const int* __restrict__ ws_order,
              const int* __restrict__ ws_flip, float* __restrict__ out)
{
  int idx = blockIdx.x * 256 + threadIdx.x;   // < 25165824, fits int
  int i = idx / NPF;
  int f = idx - i * NPF;
  int o  = ws_order[i];
  int fl = ws_flip[i];
  int r = f / 3;
  int c = f - r * 3;
  int srcf = fl ? ((1023 - r) * 3 + c) : f;
  out[idx] = edges[o * NPF + srcf];
}

extern "C" void kernel_launch(void* const* d_in, const int* in_sizes, int n_in,
                              void* d_out, int out_size, void* d_ws, size_t ws_size,
                              hipStream_t stream) {
  (void)in_sizes; (void)n_in; (void)out_size;
  const float* edges = (const float*)d_in[0];
  float* out  = (float*)d_out;
  float* tail = out + (size_t)KE * NPF;        // order | flips | distances
  int* ws_order = (int*)d_ws;
  int* ws_flip  = ws_order + KE;

  size_t off_tbl = (size_t)2 * KE * sizeof(int);              //  64 KB
  size_t off_lst = off_tbl + (size_t)KE * 8 * sizeof(float);  // +256 KB
  size_t need_lst = off_lst + (size_t)2 * KE * KNN * sizeof(u16); // +2 MB

  float* tbl   = (ws_size >= off_lst) ? (float*)((char*)d_ws + off_tbl) : nullptr;
  u16*   lists = (ws_size >= need_lst && tbl) ? (u16*)((char*)d_ws + off_lst)
                                              : nullptr;

  if (tbl)
    hipLaunchKernelGGL(tbl_build_kernel, dim3(KE / 256), dim3(256), 0, stream,
                       edges, (float4*)tbl);
  if (lists)
    hipLaunchKernelGGL(knn_kernel, dim3(2 * KE / 256), dim3(256), 0, stream,
                       (const float4*)tbl, lists);
  hipLaunchKernelGGL(chain_kernel, dim3(1), dim3(NT), 0, stream,
                     edges, tail, ws_order, ws_flip, tbl, (const u16*)lists);
  hipLaunchKernelGGL(gather_kernel, dim3((KE * NPF) / 256), dim3(256), 0, stream,
                     edges, ws_order, ws_flip, out);
}

// Round 23
// 7736.272 us; speedup vs baseline: 1.0000x; 1.0000x over previous
//
#include <hip/hip_runtime.h>
#include <math.h>
#include <float.h>

#define KE 8192        // number of edges
#define NPF 3072       // floats per edge (1024 * 3)
#define NT 512         // threads (8 waves, all run the chain redundantly)
#define EPT 16         // edges per thread
#define NW  8          // waves
#define TOPK_N 10
#define KNN 64         // candidates per list (2 windows x 2 x 32 lanes)
#define TAIL_T 7167    // main loop steps; live at tail start = 1024

typedef unsigned long long u64;
typedef unsigned short u16;
typedef float v2f __attribute__((ext_vector_type(2)));

#define GETP(arr, k) (((k) & 1) ? arr[(k) >> 1].y : arr[(k) >> 1].x)

#define DPPMIN(x, ctrl, rmask)                                              \
  do {                                                                      \
    unsigned _t = (unsigned)__builtin_amdgcn_update_dpp(                    \
        (int)0xFFFFFFFF, (int)(x), (ctrl), (rmask), 0xf, false);            \
    (x) = ((x) < _t) ? (x) : _t;                                            \
  } while (0)

#define RDL(v, l) __uint_as_float((unsigned)__builtin_amdgcn_readlane(__float_as_int(v), (l)))

// numpy-exact squared distance (no contraction) for DISCRETE decisions
__device__ __forceinline__ float dist2(float ax, float ay, float az,
                                       float bx, float by, float bz) {
#pragma clang fp contract(off)
  float dx = ax - bx, dy = ay - by, dz = az - bz;
  float s = (dx * dx + dy * dy) + dz * dz;
  return s;
}

// packed 2-edge squared distance, FMA form (argmin-safe; certified by bench)
__device__ __forceinline__ v2f dist2p(v2f cx, v2f cy, v2f cz,
                                      v2f px, v2f py, v2f pz) {
  v2f dx = px - cx, dy = py - cy, dz = pz - cz;
  return __builtin_elementwise_fma(dx, dx,
           __builtin_elementwise_fma(dy, dy, dz * dz));
}

// scalar twin of dist2p: IDENTICAL dataflow -> bitwise-identical values
__device__ __forceinline__ float dist2f(float cx, float cy, float cz,
                                        float px, float py, float pz) {
  float dx = px - cx, dy = py - cy, dz = pz - cz;
  return fmaf(dx, dx, fmaf(dy, dy, dz * dz));
}

__device__ __forceinline__ float dist3(float ax, float ay, float az,
                                       float bx, float by, float bz) {
  return sqrtf(dist2(ax, ay, az, bx, by, bz));
}

__device__ __forceinline__ u64 umin64(u64 a, u64 b) { return a < b ? a : b; }

// ---- build the compact 32B/edge endpoint table ----
extern "C" __global__ void __launch_bounds__(256)
tbl_build_kernel(const float* __restrict__ edges, float4* __restrict__ tbl4)
{
  int e = blockIdx.x * 256 + threadIdx.x;    // 8192 threads
  const float* p = edges + (size_t)e * NPF;
  float4 a, b;
  a.x = p[0]; a.y = p[1]; a.z = p[2]; a.w = p[NPF - 3];
  b.x = p[NPF - 2]; b.y = p[NPF - 1]; b.z = 0.f; b.w = 0.f;
  tbl4[(size_t)e * 2]     = a;
  tbl4[(size_t)e * 2 + 1] = b;
}

// ---- per-endpoint 64-NN edge lists (u16 indices, order = key order) ----
// f64-bitcast insertion: keys positive normals -> fmin/fmax == u64 order.
// 256-thread blocks (4 waves/CU) give the TLP to hide L2 load latency.
extern "C" __global__ void __launch_bounds__(256)
knn_kernel(const float4* __restrict__ tbl4, u16* __restrict__ lists)
{
  const int q = blockIdx.x * 256 + threadIdx.x;   // 16384 points
  float px, py, pz;
  {
    const float4* tp = tbl4 + (size_t)(q & (KE - 1)) * 2;
    float4 a = tp[0], b = tp[1];
    if (q < KE) { px = a.x; py = a.y; pz = a.z; }
    else        { px = a.w; py = b.x; pz = b.y; }
  }
  const double SENT = __longlong_as_double(0x7FE0000000000000LL); // max finite
  double kk[KNN];
#pragma unroll
  for (int i = 0; i < KNN; ++i) kk[i] = SENT;

#pragma unroll 4
  for (int e = 0; e < KE; ++e) {
    float4 a = tbl4[(size_t)e * 2];
    float4 b = tbl4[(size_t)e * 2 + 1];
    float d2s = dist2f(px, py, pz, a.x, a.y, a.z);
    float d2e = dist2f(px, py, pz, a.w, b.x, b.y);
    float v = fminf(d2s, d2e);
    double key = __longlong_as_double(
        (long long)(((u64)__float_as_uint(v) << 32) | (unsigned)e));
    if (key < kk[KNN - 1]) {
      double c = key;
#pragma unroll
      for (int j = 0; j < KNN; ++j) {
        double lo = fmin(kk[j], c);
        c         = fmax(kk[j], c);
        kk[j] = lo;
      }
    }
  }
  u16* lp = lists + (size_t)q * KNN;
#pragma unroll
  for (int i = 0; i < KNN; ++i)
    lp[i] = (u16)((u64)__double_as_longlong(kk[i]) & 0xFFFFu);
}

// R15-proven single-wave tail over the compacted 1024-entry LDS table.
__device__ void chain_tail(float& cxr, float& cyr, float& czr,
    unsigned* pk_lds, unsigned* d2_lds,
    const float4* s_ta, const float4* s_tb, int lane)
{
  constexpr int E = 16, NPT = 8;
  const int base = lane * E;
  v2f sxp[NPT], syp[NPT], szp[NPT], exp_[NPT], eyp[NPT], ezp[NPT];

#pragma unroll
  for (int e = 0; e < E; ++e) {
    float4 a = s_ta[base + e];
    float4 b = s_tb[base + e];
    if (e & 1) {
      sxp[e >> 1].y = a.x; syp[e >> 1].y = a.y; szp[e >> 1].y = a.z;
      exp_[e >> 1].y = a.w; eyp[e >> 1].y = b.x; ezp[e >> 1].y = b.y;
    } else {
      sxp[e >> 1].x = a.x; syp[e >> 1].x = a.y; szp[e >> 1].x = a.z;
      exp_[e >> 1].x = a.w; eyp[e >> 1].x = b.x; ezp[e >> 1].x = b.y;
    }
  }

  float cx = cxr, cy = cyr, cz = czr;

  for (int t = TAIL_T; t < KE - 1; ++t) {
    v2f cx2 = {cx, cx}, cy2 = {cy, cy}, cz2 = {cz, cz};
    float av0 = INFINITY, av1 = INFINITY, av2 = INFINITY, av3 = INFINITY;
    int   ai0 = 0, ai1 = 0, ai2 = 0, ai3 = 0;
#pragma unroll
    for (int p = 0; p < NPT; ++p) {
      v2f d2s = dist2p(cx2, cy2, cz2, sxp[p], syp[p], szp[p]);
      v2f d2e = dist2p(cx2, cy2, cz2, exp_[p], eyp[p], ezp[p]);
      v2f dm = __builtin_elementwise_min(d2s, d2e);
      int ix = base + 2 * p;
      int iy = base + 2 * p + 1;
      if ((p & 1) == 0) {
        if (dm.x < av0) { av0 = dm.x; ai0 = ix; }
        if (dm.y < av2) { av2 = dm.y; ai2 = iy; }
      } else {
        if (dm.x < av1) { av1 = dm.x; ai1 = ix; }
        if (dm.y < av3) { av3 = dm.y; ai3 = iy; }
      }
    }
    float mv = av0; int mi = ai0;
    if (av1 < mv || (av1 == mv && ai1 < mi)) { mv = av1; mi = ai1; }
    if (av2 < mv || (av2 == mv && ai2 < mi)) { mv = av2; mi = ai2; }
    if (av3 < mv || (av3 == mv && ai3 < mi)) { mv = av3; mi = ai3; }

    unsigned mvb = __float_as_uint(mv);
    unsigned x = mvb;
    DPPMIN(x, 0x111, 0xf);
    DPPMIN(x, 0x112, 0xf);
    DPPMIN(x, 0x114, 0xf);
    DPPMIN(x, 0x118, 0xf);
    DPPMIN(x, 0x142, 0xa);
    DPPMIN(x, 0x143, 0xc);
    unsigned wmin = (unsigned)__builtin_amdgcn_readlane((int)x, 63);

    u64 ball = __ballot(mvb == wmin);
    int win_lane = __ffsll(ball) - 1;
    int wpos = __builtin_amdgcn_readlane(mi, win_lane);

    float4 a = s_ta[wpos];
    float4 b = s_tb[wpos];
    int orig = __float_as_int(b.z);

    float da2 = dist2(cx, cy, cz, a.x, a.y, a.z);
    float db2 = dist2(cx, cy, cz, a.w, b.x, b.y);
    int fl = (sqrtf(da2) > sqrtf(db2)) ? 1 : 0;
    cx = fl ? a.x : a.w;
    cy = fl ? a.y : b.x;
    cz = fl ? a.z : b.y;

    if (lane == win_lane) {
      int e = wpos & (E - 1);
#pragma unroll
      for (int k = 0; k < NPT; ++k) {
        if ((e >> 1) == k) {
          if (e & 1) { sxp[k].y = INFINITY; exp_[k].y = INFINITY; }
          else       { sxp[k].x = INFINITY; exp_[k].x = INFINITY; }
        }
      }
      pk_lds[t + 1] = ((unsigned)orig << 1) | (unsigned)fl;
      d2_lds[t]     = wmin;
    }
  }

  cxr = cx; cyr = cy; czr = cz;
}

extern "C" __global__ void __launch_bounds__(NT, 1)
chain_kernel(const float* __restrict__ edges, float* __restrict__ tail,
             int* __restrict__ ws_order, int* __restrict__ ws_flip,
             float* __restrict__ tbl, const u16* __restrict__ lists)
{
  const int tid = threadIdx.x;
  const int lane = tid & 63;
  const int wid = tid >> 6;          // 0..7
  const int base = tid * EPT;
  const float4* tbl4 = (const float4*)tbl;

  __shared__ __align__(16) u64 kbuf[NW];
  __shared__ float  s_v[NW];
  __shared__ int    s_i[NW];
  __shared__ float  s_m1[NW], s_m2[NW];
  __shared__ unsigned pk_lds[KE];
  __shared__ unsigned d2_lds[KE];
  __shared__ unsigned bm[NW][KE / 32];          // per-WAVE private bitmaps
  __shared__ __align__(16) float4 s_ta[1024];   // tail coord table
  __shared__ __align__(16) float4 s_tb[1024];

  // zero this wave's private bitmap
  for (int i = lane; i < KE / 32; i += 64) bm[wid][i] = 0u;

  // ---- init: load endpoints into registers (512 threads x 16 edges) ----
  v2f sxp[EPT / 2], syp[EPT / 2], szp[EPT / 2];
  v2f exp_[EPT / 2], eyp[EPT / 2], ezp[EPT / 2];
#pragma unroll
  for (int e = 0; e < EPT; ++e) {
    const float* p = edges + (size_t)(base + e) * NPF;
    float a0 = p[0], a1 = p[1], a2 = p[2];
    float b0 = p[NPF - 3], b1 = p[NPF - 2], b2 = p[NPF - 1];
    if (e & 1) {
      sxp[e >> 1].y = a0; syp[e >> 1].y = a1; szp[e >> 1].y = a2;
      exp_[e >> 1].y = b0; eyp[e >> 1].y = b1; ezp[e >> 1].y = b2;
    } else {
      sxp[e >> 1].x = a0; syp[e >> 1].x = a1; szp[e >> 1].x = a2;
      exp_[e >> 1].x = b0; eyp[e >> 1].x = b1; ezp[e >> 1].x = b2;
    }
  }

  // ---- lengths; top-10; start_index = max index among them ----
  float len[EPT];
#pragma unroll
  for (int e = 0; e < EPT; ++e)
    len[e] = dist3(GETP(exp_, e), GETP(eyp, e), GETP(ezp, e),
                   GETP(sxp, e), GETP(syp, e), GETP(szp, e));

  unsigned tk = 0;
  int start_index = -1;
  for (int r = 0; r < TOPK_N; ++r) {
    float bv = -INFINITY; int bi = 0x7fffffff;
#pragma unroll
    for (int e = 0; e < EPT; ++e) {
      if ((tk >> e) & 1) continue;
      if (len[e] > bv) { bv = len[e]; bi = base + e; }
    }
    for (int m = 1; m < 64; m <<= 1) {
      float v2 = __shfl_xor(bv, m); int i2 = __shfl_xor(bi, m);
      if (v2 > bv || (v2 == bv && i2 < bi)) { bv = v2; bi = i2; }
    }
    if (lane == 0) { s_v[wid] = bv; s_i[wid] = bi; }
    __syncthreads();
    {
      float cv = s_v[lane & (NW - 1)]; int ci = s_i[lane & (NW - 1)];
      for (int m = 1; m < NW; m <<= 1) {
        float v2 = __shfl_xor(cv, m); int i2 = __shfl_xor(ci, m);
        if (v2 > cv || (v2 == cv && i2 < ci)) { cv = v2; ci = i2; }
      }
      int sel = ci;
      if ((sel / EPT) == tid) tk |= 1u << (sel & (EPT - 1));
      if (sel > start_index) start_index = sel;
    }
    __syncthreads();
  }

  // ---- s0 / e0: uniform global load ----
  float s0x, s0y, s0z, e0x, e0y, e0z;
  {
    const float* p = edges + (size_t)start_index * NPF;
    s0x = p[0];       s0y = p[1];       s0z = p[2];
    e0x = p[NPF - 3]; e0y = p[NPF - 2]; e0z = p[NPF - 1];
  }

  // ---- use_flip0 (numpy-exact; sqrt(min)==min(sqrt)) ----
  {
    float m1 = INFINITY, m2 = INFINITY;
#pragma unroll
    for (int e = 0; e < EPT; ++e) {
      int k = base + e;
      float a = dist2(s0x, s0y, s0z, GETP(sxp, e), GETP(syp, e), GETP(szp, e));
      float b = dist2(s0x, s0y, s0z, GETP(exp_, e), GETP(eyp, e), GETP(ezp, e));
      float c = dist2(e0x, e0y, e0z, GETP(sxp, e), GETP(syp, e), GETP(szp, e));
      float d = dist2(e0x, e0y, e0z, GETP(exp_, e), GETP(eyp, e), GETP(ezp, e));
      float v1 = fminf(a, b), v2 = fminf(c, d);
      if (k == start_index) { v1 = INFINITY; v2 = INFINITY; }
      m1 = fminf(m1, v1);
      m2 = fminf(m2, v2);
    }
    for (int m = 1; m < 64; m <<= 1) {
      m1 = fminf(m1, __shfl_xor(m1, m));
      m2 = fminf(m2, __shfl_xor(m2, m));
    }
    if (lane == 0) { s_m1[wid] = m1; s_m2[wid] = m2; }
  }
  __syncthreads();

  float cx, cy, cz, fx, fy, fz;
  int flip0;
  {
    float m1 = s_m1[lane & (NW - 1)], m2 = s_m2[lane & (NW - 1)];
    for (int m = 1; m < NW; m <<= 1) {
      m1 = fminf(m1, __shfl_xor(m1, m));
      m2 = fminf(m2, __shfl_xor(m2, m));
    }
    flip0 = (sqrtf(m1) < sqrtf(m2)) ? 1 : 0;
    cx = flip0 ? s0x : e0x;  cy = flip0 ? s0y : e0y;  cz = flip0 ? s0z : e0z;
    fx = flip0 ? e0x : s0x;  fy = flip0 ? e0y : s0y;  fz = flip0 ? e0z : s0z;
    if (tid == 0)
      pk_lds[0] = ((unsigned)start_index << 1) | (unsigned)flip0;
  }
  // each wave marks start edge in ITS bitmap
  if (lane == 0)
    bm[wid][start_index >> 5] |= 1u << (start_index & 31);

  // ---- warm lists (2MB) + tbl (256KB) into this XCD's L2 ----
  if (lists) {
    const float4* lp = (const float4*)lists;
    float acc = 0.f;
    for (int i = tid; i < 131072 + 16384; i += NT) {
      float4 v = (i < 131072) ? lp[i] : tbl4[i - 131072];
      acc += v.x + v.y + v.z + v.w;
    }
    asm volatile("" :: "v"(acc));
  }

  // owner of start edge: poison + clear alive
  unsigned alive = 0xFFFFu;
  if (tid == (start_index >> 4)) {
    int e = start_index & (EPT - 1);
#pragma unroll
    for (int k = 0; k < EPT / 2; ++k) {
      if ((e >> 1) == k) {
        if (e & 1) { sxp[k].y = INFINITY; exp_[k].y = INFINITY; }
        else       { sxp[k].x = INFINITY; exp_[k].x = INFINITY; }
      }
    }
    alive &= ~(1u << e);
  }
  __syncthreads();

  // bootstrap prefetch: lanes 0-31 window A (point widx), 32-63 window B;
  // each lane holds list positions (lane&31) and (lane&31)+32.
  int pf0 = 0, pf1 = 0;
  if (lists) {
    int pid = (lane < 32) ? start_index : start_index + KE;
    pf0 = (int)lists[(size_t)pid * KNN + (lane & 31)];
    pf1 = (int)lists[(size_t)pid * KNN + 32 + (lane & 31)];
  }
  int fl_prev = flip0;

  // ========== main chain: hit path barrier-free, miss path R14 ==========
  for (int t = 0; t < TAIL_T; ++t) {
    int widx; unsigned wd2;
    bool hit = false;

    if (lists) {
      int klo0 = pf0, klo1 = pf1;
      // speculative coord load for first-half candidates only
      float4 ta = tbl4[(size_t)klo0 * 2];
      float4 tb = tbl4[(size_t)klo0 * 2 + 1];
      unsigned w0 = bm[wid][klo0 >> 5];
      unsigned w1 = bm[wid][klo1 >> 5];
      int actwin = fl_prev ? 0 : 1;        // fl=1 -> new endpoint = widx
      bool act = ((lane >> 5) == actwin);
      bool un0 = act && !((w0 >> (klo0 & 31)) & 1);
      bool un1 = act && !((w1 >> (klo1 & 31)) & 1);
      u64 b0 = __ballot(un0);
      u64 b1 = __ballot(un1);
      if (b0 | b1) {
        hit = true;                        // identical across waves
        float osx, osy, osz, oex, oey, oez;
        if (b0) {                          // positions 0-31 take priority
          int first = __ffsll(b0) - 1;
          widx = __builtin_amdgcn_readlane(klo0, first);
          osx = RDL(ta.x, first); osy = RDL(ta.y, first); osz = RDL(ta.z, first);
          oex = RDL(ta.w, first); oey = RDL(tb.x, first); oez = RDL(tb.y, first);
        } else {                           // positions 32-63 (rare)
          int first = __ffsll(b1) - 1;
          widx = __builtin_amdgcn_readlane(klo1, first);
          float4 a = tbl4[(size_t)widx * 2], b_ = tbl4[(size_t)widx * 2 + 1];
          osx = a.x; osy = a.y; osz = a.z; oex = a.w; oey = b_.x; oez = b_.y;
        }
        // early bitmap publish (settles next step's read dependency)
        if (lane == 0)
          bm[wid][widx >> 5] |= 1u << (widx & 31);
        // wd2: recompute with the key's exact dataflow (fmaf scalar twin)
        float d2s = dist2f(cx, cy, cz, osx, osy, osz);
        float d2e = dist2f(cx, cy, cz, oex, oey, oez);
        wd2 = __float_as_uint(fminf(d2s, d2e));
        // flip: numpy-exact
        float da2 = dist2(cx, cy, cz, osx, osy, osz);
        float db2 = dist2(cx, cy, cz, oex, oey, oez);
        int fl = (sqrtf(da2) > sqrtf(db2)) ? 1 : 0;
        cx = fl ? osx : oex;
        cy = fl ? osy : oey;
        cz = fl ? osz : oez;
        // prefetch next lists (both windows of winner)
        int pid = (lane < 32) ? widx : widx + KE;
        pf0 = (int)lists[(size_t)pid * KNN + (lane & 31)];
        pf1 = (int)lists[(size_t)pid * KNN + 32 + (lane & 31)];
        // bookkeeping: outputs (wave0) + owner poison
        if (wid == 0 && lane == 0) {
          pk_lds[t + 1] = ((unsigned)widx << 1) | (unsigned)fl;
          d2_lds[t] = wd2;
        }
        if (tid == (widx >> 4)) {
          int e = widx & (EPT - 1);
#pragma unroll
          for (int k = 0; k < EPT / 2; ++k) {
            if ((e >> 1) == k) {
              if (e & 1) { sxp[k].y = INFINITY; exp_[k].y = INFINITY; }
              else       { sxp[k].x = INFINITY; exp_[k].x = INFINITY; }
            }
          }
          alive &= ~(1u << e);
        }
        fl_prev = fl;
      }
    }

    if (!hit) {
      // uniform across waves -> barriers are safe. R14 scan machinery.
      v2f cx2 = {cx, cx}, cy2 = {cy, cy}, cz2 = {cz, cz};
      float av0 = INFINITY, av1 = INFINITY, av2 = INFINITY, av3 = INFINITY;
      int   ai0 = 0, ai1 = 0, ai2 = 0, ai3 = 0;
#pragma unroll
      for (int p = 0; p < EPT / 2; ++p) {
        v2f d2s = dist2p(cx2, cy2, cz2, sxp[p], syp[p], szp[p]);
        v2f d2e = dist2p(cx2, cy2, cz2, exp_[p], eyp[p], ezp[p]);
        v2f dm = __builtin_elementwise_min(d2s, d2e);
        int ix = base + 2 * p;
        int iy = base + 2 * p + 1;
        if ((p & 1) == 0) {
          if (dm.x < av0) { av0 = dm.x; ai0 = ix; }
          if (dm.y < av2) { av2 = dm.y; ai2 = iy; }
        } else {
          if (dm.x < av1) { av1 = dm.x; ai1 = ix; }
          if (dm.y < av3) { av3 = dm.y; ai3 = iy; }
        }
      }
      float mv = av0; int mi = ai0;
      if (av1 < mv || (av1 == mv && ai1 < mi)) { mv = av1; mi = ai1; }
      if (av2 < mv || (av2 == mv && ai2 < mi)) { mv = av2; mi = ai2; }
      if (av3 < mv || (av3 == mv && ai3 < mi)) { mv = av3; mi = ai3; }

      unsigned mvb = __float_as_uint(mv);
      unsigned x = mvb;
      DPPMIN(x, 0x111, 0xf);
      DPPMIN(x, 0x112, 0xf);
      DPPMIN(x, 0x114, 0xf);
      DPPMIN(x, 0x118, 0xf);
      DPPMIN(x, 0x142, 0xa);
      DPPMIN(x, 0x143, 0xc);
      unsigned wmin = (unsigned)__builtin_amdgcn_readlane((int)x, 63);
      u64 ball2 = __ballot(mvb == wmin);
      int win_lane = __ffsll(ball2) - 1;
      if (lane == win_lane)
        kbuf[wid] = ((u64)wmin << 32) | (unsigned)mi;
      __syncthreads();
      const ulonglong2* kp = (const ulonglong2*)&kbuf[0];
      ulonglong2 q0 = kp[0], q1 = kp[1], q2 = kp[2], q3 = kp[3];
      u64 kb = umin64(umin64(umin64(q0.x, q0.y), umin64(q1.x, q1.y)),
                      umin64(umin64(q2.x, q2.y), umin64(q3.x, q3.y)));
      widx = __builtin_amdgcn_readfirstlane((int)(kb & 0xFFFFFFFFu));
      wd2 = (unsigned)(kb >> 32);
      __syncthreads();               // protect kbuf reuse across wave skew

      // winner coords: uniform tbl load (miss is rare)
      float osx, osy, osz, oex, oey, oez;
      if (tbl4) {
        float4 a = tbl4[(size_t)widx * 2], b = tbl4[(size_t)widx * 2 + 1];
        osx = a.x; osy = a.y; osz = a.z; oex = a.w; oey = b.x; oez = b.y;
      } else {
        const float* wp = edges + (size_t)widx * NPF;
        osx = wp[0]; osy = wp[1]; osz = wp[2];
        oex = wp[NPF - 3]; oey = wp[NPF - 2]; oez = wp[NPF - 1];
      }
      float da2 = dist2(cx, cy, cz, osx, osy, osz);
      float db2 = dist2(cx, cy, cz, oex, oey, oez);
      int fl = (sqrtf(da2) > sqrtf(db2)) ? 1 : 0;
      cx = fl ? osx : oex;
      cy = fl ? osy : oey;
      cz = fl ? osz : oez;

      if (lane == 0) {
        bm[wid][widx >> 5] |= 1u << (widx & 31);
        if (wid == 0) {
          pk_lds[t + 1] = ((unsigned)widx << 1) | (unsigned)fl;
          d2_lds[t] = wd2;
        }
      }
      if (tid == (widx >> 4)) {
        int e = widx & (EPT - 1);
#pragma unroll
        for (int k = 0; k < EPT / 2; ++k) {
          if ((e >> 1) == k) {
            if (e & 1) { sxp[k].y = INFINITY; exp_[k].y = INFINITY; }
            else       { sxp[k].x = INFINITY; exp_[k].x = INFINITY; }
          }
        }
        alive &= ~(1u << e);
      }
      if (lists) {
        int pid = (lane < 32) ? widx : widx + KE;
        pf0 = (int)lists[(size_t)pid * KNN + (lane & 31)];
        pf1 = (int)lists[(size_t)pid * KNN + 32 + (lane & 31)];
      }
      fl_prev = fl;
    }
  }

  // ---- compacted LDS table (1024 live, ascending original index) ----
  __syncthreads();
  {
    int cnt = __popc(alive);
    int sc = cnt;
#pragma unroll
    for (int m = 1; m < 64; m <<= 1) {
      int o = __shfl_up(sc, m);
      if (lane >= m) sc += o;
    }
    if (lane == 63) s_i[wid] = sc;
    __syncthreads();
    int wbase = 0;
#pragma unroll
    for (int w = 0; w < NW; ++w)
      if (w < wid) wbase += s_i[w];
    int pos = wbase + sc - cnt;
#pragma unroll
    for (int e = 0; e < EPT; ++e) {
      if ((alive >> e) & 1) {
        float4 a, b;
        a.x = GETP(sxp, e); a.y = GETP(syp, e); a.z = GETP(szp, e);
        a.w = GETP(exp_, e);
        b.x = GETP(eyp, e); b.y = GETP(ezp, e);
        b.z = __int_as_float(base + e); b.w = 0.f;
        s_ta[pos] = a; s_tb[pos] = b; ++pos;
      }
    }
  }
  __syncthreads();

  // ---- tail: compacted single-wave scan (proven R15 structure) ----
  if (wid == 0) {
    chain_tail(cx, cy, cz, pk_lds, d2_lds, s_ta, s_tb, lane);
    if (lane == 0)
      d2_lds[KE - 1] = __float_as_uint(dist2(cx, cy, cz, fx, fy, fz));
  }
  __syncthreads();

  // ---- final flush: LDS -> global (order | flips | distances | ws) ----
  float* ord_f = tail;
  float* flp_f = tail + KE;
  float* dst_f = tail + 2 * KE;
#pragma unroll
  for (int k = 0; k < EPT; ++k) {
    int i = tid + k * NT;
    unsigned p = pk_lds[i];
    int w = (int)(p >> 1);
    int f = (int)(p & 1u);
    ord_f[i] = (float)w;
    flp_f[i] = (float)f;
    dst_f[i] = sqrtf(__uint_as_float(d2_lds[i]));
    ws_order[i] = w;
    ws_flip[i]  = f;
  }
}

extern "C" __global__ void __launch_bounds__(256)
gather_kernel(const float* __restrict__ edges, const int* __restrict__ ws_order,
              const int* __restrict__ ws_flip, float* __restrict__ out)
{
  int idx = blockIdx.x * 256 + threadIdx.x;   // < 25165824, fits int
  int i = idx / NPF;
  int f = idx - i * NPF;
  int o  = ws_order[i];
  int fl = ws_flip[i];
  int r = f / 3;
  int c = f - r * 3;
  int srcf = fl ? ((1023 - r) * 3 + c) : f;
  out[idx] = edges[o * NPF + srcf];
}

extern "C" void kernel_launch(void* const* d_in, const int* in_sizes, int n_in,
                              void* d_out, int out_size, void* d_ws, size_t ws_size,
                              hipStream_t stream) {
  (void)in_sizes; (void)n_in; (void)out_size;
  const float* edges = (const float*)d_in[0];
  float* out  = (float*)d_out;
  float* tail = out + (size_t)KE * NPF;        // order | flips | distances
  int* ws_order = (int*)d_ws;
  int* ws_flip  = ws_order + KE;

  size_t off_tbl = (size_t)2 * KE * sizeof(int);              //  64 KB
  size_t off_lst = off_tbl + (size_t)KE * 8 * sizeof(float);  // +256 KB
  size_t need_lst = off_lst + (size_t)2 * KE * KNN * sizeof(u16); // +2 MB

  float* tbl   = (ws_size >= off_lst) ? (float*)((char*)d_ws + off_tbl) : nullptr;
  u16*   lists = (ws_size >= need_lst && tbl) ? (u16*)((char*)d_ws + off_lst)
                                              : nullptr;

  if (tbl)
    hipLaunchKernelGGL(tbl_build_kernel, dim3(KE / 256), dim3(256), 0, stream,
                       edges, (float4*)tbl);
  if (lists)
    hipLaunchKernelGGL(knn_kernel, dim3(2 * KE / 256), dim3(256), 0, stream,
                       (const float4*)tbl, lists);
  hipLaunchKernelGGL(chain_kernel, dim3(1), dim3(NT), 0, stream,
                     edges, tail, ws_order, ws_flip, tbl, (const u16*)lists);
  hipLaunchKernelGGL(gather_kernel, dim3((KE * NPF) / 256), dim3(256), 0, stream,
                     edges, ws_order, ws_flip, out);
}

// Round 24
// 4977.557 us; speedup vs baseline: 1.5543x; 1.5542x over previous
//
#include <hip/hip_runtime.h>
#include <math.h>
#include <float.h>

#define KE 8192        // number of edges
#define NPF 3072       // floats per edge (1024 * 3)
#define NT 512         // threads (8 waves, all run the chain redundantly)
#define EPT 16         // edges per thread
#define NW  8          // waves
#define TOPK_N 10
#define KNN 32         // candidates per list (2 windows x 32 = 64 lanes)
#define NPART 4        // knn partial scans per point
#define TAIL_T 7167    // main loop steps; live at tail start = 1024

typedef unsigned long long u64;
typedef unsigned short u16;
typedef float v2f __attribute__((ext_vector_type(2)));

#define GETP(arr, k) (((k) & 1) ? arr[(k) >> 1].y : arr[(k) >> 1].x)

#define DPPMIN(x, ctrl, rmask)                                              \
  do {                                                                      \
    unsigned _t = (unsigned)__builtin_amdgcn_update_dpp(                    \
        (int)0xFFFFFFFF, (int)(x), (ctrl), (rmask), 0xf, false);            \
    (x) = ((x) < _t) ? (x) : _t;                                            \
  } while (0)

#define RDL(v, l) __uint_as_float((unsigned)__builtin_amdgcn_readlane(__float_as_int(v), (l)))

// numpy-exact squared distance (no contraction) for DISCRETE decisions
__device__ __forceinline__ float dist2(float ax, float ay, float az,
                                       float bx, float by, float bz) {
#pragma clang fp contract(off)
  float dx = ax - bx, dy = ay - by, dz = az - bz;
  float s = (dx * dx + dy * dy) + dz * dz;
  return s;
}

// packed 2-edge squared distance, FMA form (argmin-safe; certified by bench)
__device__ __forceinline__ v2f dist2p(v2f cx, v2f cy, v2f cz,
                                      v2f px, v2f py, v2f pz) {
  v2f dx = px - cx, dy = py - cy, dz = pz - cz;
  return __builtin_elementwise_fma(dx, dx,
           __builtin_elementwise_fma(dy, dy, dz * dz));
}

// scalar twin of dist2p: IDENTICAL dataflow -> bitwise-identical values
__device__ __forceinline__ float dist2f(float cx, float cy, float cz,
                                        float px, float py, float pz) {
  float dx = px - cx, dy = py - cy, dz = pz - cz;
  return fmaf(dx, dx, fmaf(dy, dy, dz * dz));
}

__device__ __forceinline__ float dist3(float ax, float ay, float az,
                                       float bx, float by, float bz) {
  return sqrtf(dist2(ax, ay, az, bx, by, bz));
}

__device__ __forceinline__ u64 umin64(u64 a, u64 b) { return a < b ? a : b; }

// ---- build the compact 32B/edge endpoint table ----
extern "C" __global__ void __launch_bounds__(256)
tbl_build_kernel(const float* __restrict__ edges, float4* __restrict__ tbl4)
{
  int e = blockIdx.x * 256 + threadIdx.x;    // 8192 threads
  const float* p = edges + (size_t)e * NPF;
  float4 a, b;
  a.x = p[0]; a.y = p[1]; a.z = p[2]; a.w = p[NPF - 3];
  b.x = p[NPF - 2]; b.y = p[NPF - 1]; b.z = 0.f; b.w = 0.f;
  tbl4[(size_t)e * 2]     = a;
  tbl4[(size_t)e * 2 + 1] = b;
}

// ---- FALLBACK: monolithic per-endpoint 32-NN (R21-proven) ----
extern "C" __global__ void __launch_bounds__(64)
knn_kernel(const float4* __restrict__ tbl4, u16* __restrict__ lists)
{
  const int q = blockIdx.x * 64 + threadIdx.x;   // 16384 points
  float px, py, pz;
  {
    const float4* tp = tbl4 + (size_t)(q & (KE - 1)) * 2;
    float4 a = tp[0], b = tp[1];
    if (q < KE) { px = a.x; py = a.y; pz = a.z; }
    else        { px = a.w; py = b.x; pz = b.y; }
  }
  const double SENT = __longlong_as_double(0x7FE0000000000000LL);
  double kk[KNN];
#pragma unroll
  for (int i = 0; i < KNN; ++i) kk[i] = SENT;

#pragma unroll 4
  for (int e = 0; e < KE; ++e) {
    float4 a = tbl4[(size_t)e * 2];
    float4 b = tbl4[(size_t)e * 2 + 1];
    float d2s = dist2f(px, py, pz, a.x, a.y, a.z);
    float d2e = dist2f(px, py, pz, a.w, b.x, b.y);
    float v = fminf(d2s, d2e);
    double key = __longlong_as_double(
        (long long)(((u64)__float_as_uint(v) << 32) | (unsigned)e));
    if (key < kk[KNN - 1]) {
      double c = key;
#pragma unroll
      for (int j = 0; j < KNN; ++j) {
        double lo = fmin(kk[j], c);
        c         = fmax(kk[j], c);
        kk[j] = lo;
      }
    }
  }
  u16* lp = lists + (size_t)q * KNN;
#pragma unroll
  for (int i = 0; i < KNN; ++i)
    lp[i] = (u16)((u64)__double_as_longlong(kk[i]) & 0xFFFFu);
}

// ---- SPLIT knn: 4 partial scans per point (4x the wave parallelism) ----
// part = blockIdx>>6 (wave-uniform edge range -> broadcast tbl loads);
// q = (blockIdx&63)*256 + threadIdx. Exact sorted top-32 of its range.
extern "C" __global__ void __launch_bounds__(256)
knn_partial_kernel(const float4* __restrict__ tbl4, u64* __restrict__ plists)
{
  const int part = blockIdx.x >> 6;               // 0..3
  const int q = (blockIdx.x & 63) * 256 + threadIdx.x;   // 16384 points
  const int e0 = part * (KE / NPART);
  float px, py, pz;
  {
    const float4* tp = tbl4 + (size_t)(q & (KE - 1)) * 2;
    float4 a = tp[0], b = tp[1];
    if (q < KE) { px = a.x; py = a.y; pz = a.z; }
    else        { px = a.w; py = b.x; pz = b.y; }
  }
  const double SENT = __longlong_as_double(0x7FE0000000000000LL);
  double kk[KNN];
#pragma unroll
  for (int i = 0; i < KNN; ++i) kk[i] = SENT;

#pragma unroll 4
  for (int ee = 0; ee < KE / NPART; ++ee) {
    int e = e0 + ee;
    float4 a = tbl4[(size_t)e * 2];
    float4 b = tbl4[(size_t)e * 2 + 1];
    float d2s = dist2f(px, py, pz, a.x, a.y, a.z);
    float d2e = dist2f(px, py, pz, a.w, b.x, b.y);
    float v = fminf(d2s, d2e);
    double key = __longlong_as_double(
        (long long)(((u64)__float_as_uint(v) << 32) | (unsigned)e));
    if (key < kk[KNN - 1]) {
      double c = key;
#pragma unroll
      for (int j = 0; j < KNN; ++j) {
        double lo = fmin(kk[j], c);
        c         = fmax(kk[j], c);
        kk[j] = lo;
      }
    }
  }
  u64* lp = plists + ((size_t)q * NPART + part) * KNN;
#pragma unroll
  for (int i = 0; i < KNN; ++i)
    lp[i] = (u64)__double_as_longlong(kk[i]);
}

// ---- merge 4 sorted partial lists -> exact global top-32 (u16) ----
// Keys are unique ((d2bits<<32)|idx), so equality identifies the source.
extern "C" __global__ void __launch_bounds__(256)
knn_merge_kernel(const u64* __restrict__ plists, u16* __restrict__ lists)
{
  const int q = blockIdx.x * 256 + threadIdx.x;   // 16384 points
  const u64* p0 = plists + ((size_t)q * NPART + 0) * KNN;
  const u64* p1 = plists + ((size_t)q * NPART + 1) * KNN;
  const u64* p2 = plists + ((size_t)q * NPART + 2) * KNN;
  const u64* p3 = plists + ((size_t)q * NPART + 3) * KNN;
  u64 h0 = p0[0], h1 = p1[0], h2 = p2[0], h3 = p3[0];
  int i0 = 1, i1 = 1, i2 = 1, i3 = 1;
  u16* lp = lists + (size_t)q * KNN;
#pragma unroll 1
  for (int j = 0; j < KNN; ++j) {
    u64 m = umin64(umin64(h0, h1), umin64(h2, h3));
    lp[j] = (u16)(m & 0xFFFFu);
    if (m == h0)      h0 = (i0 < KNN) ? p0[i0++] : ~0ull;
    else if (m == h1) h1 = (i1 < KNN) ? p1[i1++] : ~0ull;
    else if (m == h2) h2 = (i2 < KNN) ? p2[i2++] : ~0ull;
    else              h3 = (i3 < KNN) ? p3[i3++] : ~0ull;
  }
}

// R15-proven single-wave tail over the compacted 1024-entry LDS table.
__device__ void chain_tail(float& cxr, float& cyr, float& czr,
    unsigned* pk_lds, unsigned* d2_lds,
    const float4* s_ta, const float4* s_tb, int lane)
{
  constexpr int E = 16, NPT = 8;
  const int base = lane * E;
  v2f sxp[NPT], syp[NPT], szp[NPT], exp_[NPT], eyp[NPT], ezp[NPT];

#pragma unroll
  for (int e = 0; e < E; ++e) {
    float4 a = s_ta[base + e];
    float4 b = s_tb[base + e];
    if (e & 1) {
      sxp[e >> 1].y = a.x; syp[e >> 1].y = a.y; szp[e >> 1].y = a.z;
      exp_[e >> 1].y = a.w; eyp[e >> 1].y = b.x; ezp[e >> 1].y = b.y;
    } else {
      sxp[e >> 1].x = a.x; syp[e >> 1].x = a.y; szp[e >> 1].x = a.z;
      exp_[e >> 1].x = a.w; eyp[e >> 1].x = b.x; ezp[e >> 1].x = b.y;
    }
  }

  float cx = cxr, cy = cyr, cz = czr;

  for (int t = TAIL_T; t < KE - 1; ++t) {
    v2f cx2 = {cx, cx}, cy2 = {cy, cy}, cz2 = {cz, cz};
    float av0 = INFINITY, av1 = INFINITY, av2 = INFINITY, av3 = INFINITY;
    int   ai0 = 0, ai1 = 0, ai2 = 0, ai3 = 0;
#pragma unroll
    for (int p = 0; p < NPT; ++p) {
      v2f d2s = dist2p(cx2, cy2, cz2, sxp[p], syp[p], szp[p]);
      v2f d2e = dist2p(cx2, cy2, cz2, exp_[p], eyp[p], ezp[p]);
      v2f dm = __builtin_elementwise_min(d2s, d2e);
      int ix = base + 2 * p;
      int iy = base + 2 * p + 1;
      if ((p & 1) == 0) {
        if (dm.x < av0) { av0 = dm.x; ai0 = ix; }
        if (dm.y < av2) { av2 = dm.y; ai2 = iy; }
      } else {
        if (dm.x < av1) { av1 = dm.x; ai1 = ix; }
        if (dm.y < av3) { av3 = dm.y; ai3 = iy; }
      }
    }
    float mv = av0; int mi = ai0;
    if (av1 < mv || (av1 == mv && ai1 < mi)) { mv = av1; mi = ai1; }
    if (av2 < mv || (av2 == mv && ai2 < mi)) { mv = av2; mi = ai2; }
    if (av3 < mv || (av3 == mv && ai3 < mi)) { mv = av3; mi = ai3; }

    unsigned mvb = __float_as_uint(mv);
    unsigned x = mvb;
    DPPMIN(x, 0x111, 0xf);
    DPPMIN(x, 0x112, 0xf);
    DPPMIN(x, 0x114, 0xf);
    DPPMIN(x, 0x118, 0xf);
    DPPMIN(x, 0x142, 0xa);
    DPPMIN(x, 0x143, 0xc);
    unsigned wmin = (unsigned)__builtin_amdgcn_readlane((int)x, 63);

    u64 ball = __ballot(mvb == wmin);
    int win_lane = __ffsll(ball) - 1;
    int wpos = __builtin_amdgcn_readlane(mi, win_lane);

    float4 a = s_ta[wpos];
    float4 b = s_tb[wpos];
    int orig = __float_as_int(b.z);

    float da2 = dist2(cx, cy, cz, a.x, a.y, a.z);
    float db2 = dist2(cx, cy, cz, a.w, b.x, b.y);
    int fl = (sqrtf(da2) > sqrtf(db2)) ? 1 : 0;
    cx = fl ? a.x : a.w;
    cy = fl ? a.y : b.x;
    cz = fl ? a.z : b.y;

    if (lane == win_lane) {
      int e = wpos & (E - 1);
#pragma unroll
      for (int k = 0; k < NPT; ++k) {
        if ((e >> 1) == k) {
          if (e & 1) { sxp[k].y = INFINITY; exp_[k].y = INFINITY; }
          else       { sxp[k].x = INFINITY; exp_[k].x = INFINITY; }
        }
      }
      pk_lds[t + 1] = ((unsigned)orig << 1) | (unsigned)fl;
      d2_lds[t]     = wmin;
    }
  }

  cxr = cx; cyr = cy; czr = cz;
}

extern "C" __global__ void __launch_bounds__(NT, 1)
chain_kernel(const float* __restrict__ edges, float* __restrict__ tail,
             int* __restrict__ ws_order, int* __restrict__ ws_flip,
             float* __restrict__ tbl, const u16* __restrict__ lists)
{
  const int tid = threadIdx.x;
  const int lane = tid & 63;
  const int wid = tid >> 6;          // 0..7
  const int base = tid * EPT;
  const float4* tbl4 = (const float4*)tbl;

  __shared__ __align__(16) u64 kbuf[NW];
  __shared__ float  s_v[NW];
  __shared__ int    s_i[NW];
  __shared__ float  s_m1[NW], s_m2[NW];
  __shared__ unsigned pk_lds[KE];
  __shared__ unsigned d2_lds[KE];
  __shared__ unsigned bm[NW][KE / 32];          // per-WAVE private bitmaps
  __shared__ __align__(16) float4 s_ta[1024];   // tail coord table
  __shared__ __align__(16) float4 s_tb[1024];

  // zero this wave's private bitmap
  for (int i = lane; i < KE / 32; i += 64) bm[wid][i] = 0u;

  // ---- init: load endpoints into registers (512 threads x 16 edges) ----
  v2f sxp[EPT / 2], syp[EPT / 2], szp[EPT / 2];
  v2f exp_[EPT / 2], eyp[EPT / 2], ezp[EPT / 2];
#pragma unroll
  for (int e = 0; e < EPT; ++e) {
    const float* p = edges + (size_t)(base + e) * NPF;
    float a0 = p[0], a1 = p[1], a2 = p[2];
    float b0 = p[NPF - 3], b1 = p[NPF - 2], b2 = p[NPF - 1];
    if (e & 1) {
      sxp[e >> 1].y = a0; syp[e >> 1].y = a1; szp[e >> 1].y = a2;
      exp_[e >> 1].y = b0; eyp[e >> 1].y = b1; ezp[e >> 1].y = b2;
    } else {
      sxp[e >> 1].x = a0; syp[e >> 1].x = a1; szp[e >> 1].x = a2;
      exp_[e >> 1].x = b0; eyp[e >> 1].x = b1; ezp[e >> 1].x = b2;
    }
  }

  // ---- lengths; top-10; start_index = max index among them ----
  float len[EPT];
#pragma unroll
  for (int e = 0; e < EPT; ++e)
    len[e] = dist3(GETP(exp_, e), GETP(eyp, e), GETP(ezp, e),
                   GETP(sxp, e), GETP(syp, e), GETP(szp, e));

  unsigned tk = 0;
  int start_index = -1;
  for (int r = 0; r < TOPK_N; ++r) {
    float bv = -INFINITY; int bi = 0x7fffffff;
#pragma unroll
    for (int e = 0; e < EPT; ++e) {
      if ((tk >> e) & 1) continue;
      if (len[e] > bv) { bv = len[e]; bi = base + e; }
    }
    for (int m = 1; m < 64; m <<= 1) {
      float v2 = __shfl_xor(bv, m); int i2 = __shfl_xor(bi, m);
      if (v2 > bv || (v2 == bv && i2 < bi)) { bv = v2; bi = i2; }
    }
    if (lane == 0) { s_v[wid] = bv; s_i[wid] = bi; }
    __syncthreads();
    {
      float cv = s_v[lane & (NW - 1)]; int ci = s_i[lane & (NW - 1)];
      for (int m = 1; m < NW; m <<= 1) {
        float v2 = __shfl_xor(cv, m); int i2 = __shfl_xor(ci, m);
        if (v2 > cv || (v2 == cv && i2 < ci)) { cv = v2; ci = i2; }
      }
      int sel = ci;
      if ((sel / EPT) == tid) tk |= 1u << (sel & (EPT - 1));
      if (sel > start_index) start_index = sel;
    }
    __syncthreads();
  }

  // ---- s0 / e0: uniform global load ----
  float s0x, s0y, s0z, e0x, e0y, e0z;
  {
    const float* p = edges + (size_t)start_index * NPF;
    s0x = p[0];       s0y = p[1];       s0z = p[2];
    e0x = p[NPF - 3]; e0y = p[NPF - 2]; e0z = p[NPF - 1];
  }

  // ---- use_flip0 (numpy-exact; sqrt(min)==min(sqrt)) ----
  {
    float m1 = INFINITY, m2 = INFINITY;
#pragma unroll
    for (int e = 0; e < EPT; ++e) {
      int k = base + e;
      float a = dist2(s0x, s0y, s0z, GETP(sxp, e), GETP(syp, e), GETP(szp, e));
      float b = dist2(s0x, s0y, s0z, GETP(exp_, e), GETP(eyp, e), GETP(ezp, e));
      float c = dist2(e0x, e0y, e0z, GETP(sxp, e), GETP(syp, e), GETP(szp, e));
      float d = dist2(e0x, e0y, e0z, GETP(exp_, e), GETP(eyp, e), GETP(ezp, e));
      float v1 = fminf(a, b), v2 = fminf(c, d);
      if (k == start_index) { v1 = INFINITY; v2 = INFINITY; }
      m1 = fminf(m1, v1);
      m2 = fminf(m2, v2);
    }
    for (int m = 1; m < 64; m <<= 1) {
      m1 = fminf(m1, __shfl_xor(m1, m));
      m2 = fminf(m2, __shfl_xor(m2, m));
    }
    if (lane == 0) { s_m1[wid] = m1; s_m2[wid] = m2; }
  }
  __syncthreads();

  float cx, cy, cz, fx, fy, fz;
  int flip0;
  {
    float m1 = s_m1[lane & (NW - 1)], m2 = s_m2[lane & (NW - 1)];
    for (int m = 1; m < NW; m <<= 1) {
      m1 = fminf(m1, __shfl_xor(m1, m));
      m2 = fminf(m2, __shfl_xor(m2, m));
    }
    flip0 = (sqrtf(m1) < sqrtf(m2)) ? 1 : 0;
    cx = flip0 ? s0x : e0x;  cy = flip0 ? s0y : e0y;  cz = flip0 ? s0z : e0z;
    fx = flip0 ? e0x : s0x;  fy = flip0 ? e0y : s0y;  fz = flip0 ? e0z : s0z;
    if (tid == 0)
      pk_lds[0] = ((unsigned)start_index << 1) | (unsigned)flip0;
  }
  // each wave marks start edge in ITS bitmap
  if (lane == 0)
    bm[wid][start_index >> 5] |= 1u << (start_index & 31);

  // ---- warm lists (1MB) + tbl (256KB) into this XCD's L2 ----
  if (lists) {
    const float4* lp = (const float4*)lists;
    float acc = 0.f;
    for (int i = tid; i < 65536 + 16384; i += NT) {
      float4 v = (i < 65536) ? lp[i] : tbl4[i - 65536];
      acc += v.x + v.y + v.z + v.w;
    }
    asm volatile("" :: "v"(acc));
  }

  // owner of start edge: poison + clear alive
  unsigned alive = 0xFFFFu;
  if (tid == (start_index >> 4)) {
    int e = start_index & (EPT - 1);
#pragma unroll
    for (int k = 0; k < EPT / 2; ++k) {
      if ((e >> 1) == k) {
        if (e & 1) { sxp[k].y = INFINITY; exp_[k].y = INFINITY; }
        else       { sxp[k].x = INFINITY; exp_[k].x = INFINITY; }
      }
    }
    alive &= ~(1u << e);
  }
  __syncthreads();

  // bootstrap prefetch: lanes 0-31 = point widx, lanes 32-63 = point widx+KE
  int pf = 0;
  if (lists) {
    int pid = (lane < 32) ? start_index : start_index + KE;
    pf = (int)lists[(size_t)pid * KNN + (lane & 31)];
  }
  int fl_prev = flip0;

  // ========== main chain: hit path barrier-free, miss path R14 ==========
  for (int t = 0; t < TAIL_T; ++t) {
    int widx; unsigned wd2;
    bool hit = false;

    if (lists) {
      // lane's own candidate; speculative coord load overlaps bitmap check
      int klo = pf;
      float4 ta = tbl4[(size_t)klo * 2];
      float4 tb = tbl4[(size_t)klo * 2 + 1];
      unsigned w = bm[wid][klo >> 5];
      int actwin = fl_prev ? 0 : 1;        // fl=1 -> new endpoint = widx
      bool unused = ((lane >> 5) == actwin) && !((w >> (klo & 31)) & 1);
      u64 ball = __ballot(unused);
      if (ball) {
        hit = true;                        // identical across waves
        int first = __ffsll(ball) - 1;
        widx = __builtin_amdgcn_readlane(klo, first);
        // broadcast winner coords from its lane (no serial tbl load)
        float osx = RDL(ta.x, first), osy = RDL(ta.y, first), osz = RDL(ta.z, first);
        float oex = RDL(ta.w, first), oey = RDL(tb.x, first), oez = RDL(tb.y, first);
        // early bitmap publish (settles next step's read dependency)
        if (lane == 0)
          bm[wid][widx >> 5] |= 1u << (widx & 31);
        // wd2: recompute with the key's exact dataflow (fmaf scalar twin)
        float d2s = dist2f(cx, cy, cz, osx, osy, osz);
        float d2e = dist2f(cx, cy, cz, oex, oey, oez);
        wd2 = __float_as_uint(fminf(d2s, d2e));
        // flip: numpy-exact
        float da2 = dist2(cx, cy, cz, osx, osy, osz);
        float db2 = dist2(cx, cy, cz, oex, oey, oez);
        int fl = (sqrtf(da2) > sqrtf(db2)) ? 1 : 0;
        cx = fl ? osx : oex;
        cy = fl ? osy : oey;
        cz = fl ? osz : oez;
        // prefetch next lists (both windows of winner)
        int pid = (lane < 32) ? widx : widx + KE;
        pf = (int)lists[(size_t)pid * KNN + (lane & 31)];
        // bookkeeping: outputs (wave0) + owner poison
        if (wid == 0 && lane == 0) {
          pk_lds[t + 1] = ((unsigned)widx << 1) | (unsigned)fl;
          d2_lds[t] = wd2;
        }
        if (tid == (widx >> 4)) {
          int e = widx & (EPT - 1);
#pragma unroll
          for (int k = 0; k < EPT / 2; ++k) {
            if ((e >> 1) == k) {
              if (e & 1) { sxp[k].y = INFINITY; exp_[k].y = INFINITY; }
              else       { sxp[k].x = INFINITY; exp_[k].x = INFINITY; }
            }
          }
          alive &= ~(1u << e);
        }
        fl_prev = fl;
      }
    }

    if (!hit) {
      // uniform across waves -> barriers are safe. R14 scan machinery.
      v2f cx2 = {cx, cx}, cy2 = {cy, cy}, cz2 = {cz, cz};
      float av0 = INFINITY, av1 = INFINITY, av2 = INFINITY, av3 = INFINITY;
      int   ai0 = 0, ai1 = 0, ai2 = 0, ai3 = 0;
#pragma unroll
      for (int p = 0; p < EPT / 2; ++p) {
        v2f d2s = dist2p(cx2, cy2, cz2, sxp[p], syp[p], szp[p]);
        v2f d2e = dist2p(cx2, cy2, cz2, exp_[p], eyp[p], ezp[p]);
        v2f dm = __builtin_elementwise_min(d2s, d2e);
        int ix = base + 2 * p;
        int iy = base + 2 * p + 1;
        if ((p & 1) == 0) {
          if (dm.x < av0) { av0 = dm.x; ai0 = ix; }
          if (dm.y < av2) { av2 = dm.y; ai2 = iy; }
        } else {
          if (dm.x < av1) { av1 = dm.x; ai1 = ix; }
          if (dm.y < av3) { av3 = dm.y; ai3 = iy; }
        }
      }
      float mv = av0; int mi = ai0;
      if (av1 < mv || (av1 == mv && ai1 < mi)) { mv = av1; mi = ai1; }
      if (av2 < mv || (av2 == mv && ai2 < mi)) { mv = av2; mi = ai2; }
      if (av3 < mv || (av3 == mv && ai3 < mi)) { mv = av3; mi = ai3; }

      unsigned mvb = __float_as_uint(mv);
      unsigned x = mvb;
      DPPMIN(x, 0x111, 0xf);
      DPPMIN(x, 0x112, 0xf);
      DPPMIN(x, 0x114, 0xf);
      DPPMIN(x, 0x118, 0xf);
      DPPMIN(x, 0x142, 0xa);
      DPPMIN(x, 0x143, 0xc);
      unsigned wmin = (unsigned)__builtin_amdgcn_readlane((int)x, 63);
      u64 ball2 = __ballot(mvb == wmin);
      int win_lane = __ffsll(ball2) - 1;
      if (lane == win_lane)
        kbuf[wid] = ((u64)wmin << 32) | (unsigned)mi;
      __syncthreads();
      const ulonglong2* kp = (const ulonglong2*)&kbuf[0];
      ulonglong2 q0 = kp[0], q1 = kp[1], q2 = kp[2], q3 = kp[3];
      u64 kb = umin64(umin64(umin64(q0.x, q0.y), umin64(q1.x, q1.y)),
                      umin64(umin64(q2.x, q2.y), umin64(q3.x, q3.y)));
      widx = __builtin_amdgcn_readfirstlane((int)(kb & 0xFFFFFFFFu));
      wd2 = (unsigned)(kb >> 32);
      __syncthreads();               // protect kbuf reuse across wave skew

      // winner coords: uniform tbl load (miss is rare)
      float osx, osy, osz, oex, oey, oez;
      if (tbl4) {
        float4 a = tbl4[(size_t)widx * 2], b = tbl4[(size_t)widx * 2 + 1];
        osx = a.x; osy = a.y; osz = a.z; oex = a.w; oey = b.x; oez = b.y;
      } else {
        const float* wp = edges + (size_t)widx * NPF;
        osx = wp[0]; osy = wp[1]; osz = wp[2];
        oex = wp[NPF - 3]; oey = wp[NPF - 2]; oez = wp[NPF - 1];
      }
      float da2 = dist2(cx, cy, cz, osx, osy, osz);
      float db2 = dist2(cx, cy, cz, oex, oey, oez);
      int fl = (sqrtf(da2) > sqrtf(db2)) ? 1 : 0;
      cx = fl ? osx : oex;
      cy = fl ? osy : oey;
      cz = fl ? osz : oez;

      if (lane == 0) {
        bm[wid][widx >> 5] |= 1u << (widx & 31);
        if (wid == 0) {
          pk_lds[t + 1] = ((unsigned)widx << 1) | (unsigned)fl;
          d2_lds[t] = wd2;
        }
      }
      if (tid == (widx >> 4)) {
        int e = widx & (EPT - 1);
#pragma unroll
        for (int k = 0; k < EPT / 2; ++k) {
          if ((e >> 1) == k) {
            if (e & 1) { sxp[k].y = INFINITY; exp_[k].y = INFINITY; }
            else       { sxp[k].x = INFINITY; exp_[k].x = INFINITY; }
          }
        }
        alive &= ~(1u << e);
      }
      if (lists) {
        int pid = (lane < 32) ? widx : widx + KE;
        pf = (int)lists[(size_t)pid * KNN + (lane & 31)];
      }
      fl_prev = fl;
    }
  }

  // ---- compacted LDS table (1024 live, ascending original index) ----
  __syncthreads();
  {
    int cnt = __popc(alive);
    int sc = cnt;
#pragma unroll
    for (int m = 1; m < 64; m <<= 1) {
      int o = __shfl_up(sc, m);
      if (lane >= m) sc += o;
    }
    if (lane == 63) s_i[wid] = sc;
    __syncthreads();
    int wbase = 0;
#pragma unroll
    for (int w = 0; w < NW; ++w)
      if (w < wid) wbase += s_i[w];
    int pos = wbase + sc - cnt;
#pragma unroll
    for (int e = 0; e < EPT; ++e) {
      if ((alive >> e) & 1) {
        float4 a, b;
        a.x = GETP(sxp, e); a.y = GETP(syp, e); a.z = GETP(szp, e);
        a.w = GETP(exp_, e);
        b.x = GETP(eyp, e); b.y = GETP(ezp, e);
        b.z = __int_as_float(base + e); b.w = 0.f;
        s_ta[pos] = a; s_tb[pos] = b; ++pos;
      }
    }
  }
  __syncthreads();

  // ---- tail: compacted single-wave scan (proven R15 structure) ----
  if (wid == 0) {
    chain_tail(cx, cy, cz, pk_lds, d2_lds, s_ta, s_tb, lane);
    if (lane == 0)
      d2_lds[KE - 1] = __float_as_uint(dist2(cx, cy, cz, fx, fy, fz));
  }
  __syncthreads();

  // ---- final flush: LDS -> global (order | flips | distances | ws) ----
  float* ord_f = tail;
  float* flp_f = tail + KE;
  float* dst_f = tail + 2 * KE;
#pragma unroll
  for (int k = 0; k < EPT; ++k) {
    int i = tid + k * NT;
    unsigned p = pk_lds[i];
    int w = (int)(p >> 1);
    int f = (int)(p & 1u);
    ord_f[i] = (float)w;
    flp_f[i] = (float)f;
    dst_f[i] = sqrtf(__uint_as_float(d2_lds[i]));
    ws_order[i] = w;
    ws_flip[i]  = f;
  }
}

extern "C" __global__ void __launch_bounds__(256)
gather_kernel(const float* __restrict__ edges, const int* __restrict__ ws_order,
              const int* __restrict__ ws_flip, float* __restrict__ out)
{
  int idx = blockIdx.x * 256 + threadIdx.x;   // < 25165824, fits int
  int i = idx / NPF;
  int f = idx - i * NPF;
  int o  = ws_order[i];
  int fl = ws_flip[i];
  int r = f / 3;
  int c = f - r * 3;
  int srcf = fl ? ((1023 - r) * 3 + c) : f;
  out[idx] = edges[o * NPF + srcf];
}

extern "C" void kernel_launch(void* const* d_in, const int* in_sizes, int n_in,
                              void* d_out, int out_size, void* d_ws, size_t ws_size,
                              hipStream_t stream) {
  (void)in_sizes; (void)n_in; (void)out_size;
  const float* edges = (const float*)d_in[0];
  float* out  = (float*)d_out;
  float* tail = out + (size_t)KE * NPF;        // order | flips | distances
  int* ws_order = (int*)d_ws;
  int* ws_flip  = ws_order + KE;

  size_t off_tbl  = (size_t)2 * KE * sizeof(int);              //  64 KB
  size_t off_lst  = off_tbl + (size_t)KE * 8 * sizeof(float);  // +256 KB
  size_t off_part = off_lst + (size_t)2 * KE * KNN * sizeof(u16); // +1 MB
  size_t need_lst  = off_part;
  size_t need_part = off_part + (size_t)2 * KE * NPART * KNN * sizeof(u64); // +16 MB

  float* tbl   = (ws_size >= off_lst) ? (float*)((char*)d_ws + off_tbl) : nullptr;
  u16*   lists = (ws_size >= need_lst && tbl) ? (u16*)((char*)d_ws + off_lst)
                                              : nullptr;
  u64*   plists = (ws_size >= need_part && lists)
                    ? (u64*)((char*)d_ws + off_part) : nullptr;

  if (tbl)
    hipLaunchKernelGGL(tbl_build_kernel, dim3(KE / 256), dim3(256), 0, stream,
                       edges, (float4*)tbl);
  if (plists) {
    hipLaunchKernelGGL(knn_partial_kernel, dim3(64 * NPART), dim3(256), 0,
                       stream, (const float4*)tbl, plists);
    hipLaunchKernelGGL(knn_merge_kernel, dim3(2 * KE / 256), dim3(256), 0,
                       stream, (const u64*)plists, lists);
  } else if (lists) {
    hipLaunchKernelGGL(knn_kernel, dim3(2 * KE / 64), dim3(64), 0, stream,
                       (const float4*)tbl, lists);
  }
  hipLaunchKernelGGL(chain_kernel, dim3(1), dim3(NT), 0, stream,
                     edges, tail, ws_order, ws_flip, tbl, (const u16*)lists);
  hipLaunchKernelGGL(gather_kernel, dim3((KE * NPF) / 256), dim3(256), 0, stream,
                     edges, ws_order, ws_flip, out);
}